// Round 14
// baseline (39.365 us; speedup 1.0000x reference)
//
#include <hip/hip_runtime.h>
#include <hip/hip_fp16.h>

// NeuMF forward via v_mfma_f32_16x16x32_f16 (gfx950, 4-pass, short latency).
// 16-sample tiles; lane = n + 16g, g = lane>>4 (group 0..3).
//   A[m][k]: m = lane&15, k = 4g + (e&3) + 16*(e>>2), e=0..7
//   B[k][n]: n = lane&15, k = same formula
//   D[m][n]: n = lane&15, m = 4g + r, reg r=0..3
// Chain identity: B_next ktile kt elems{0-3,4-7} = relu(d_prev[2kt],[2kt+1])
// (same lane, same sample) -> zero cross-lane between layers.
// Input B1 (K=32): g0 e0-3 = eU(k0-3), g1 e0-3 = eV(k4-7), g2 e0 = 1.0 (k8
// bias, A1 col8 = b1), rest 0. Layer2 K=64: 2 k-tiles; k=50 bias = ktile1
// elem6 on g0 (A2 col50 = b2). Layer3 = 4 v_dot2 + shfl_xor(16,32) reduce.
// Why this shape: 32x32 MFMA is 16-pass/long-latency; its 7-deep serial
// chain stalled 4 waves/SIMD at ~885cyc/tile. 16x16x32 halves chain length
// and D-register footprint (d1 16, d2 8, z 4 regs) -> 5 waves/SIMD.

typedef __attribute__((ext_vector_type(4))) float    f32x4;
typedef __attribute__((ext_vector_type(8))) _Float16 f16x8;
typedef __attribute__((ext_vector_type(2))) _Float16 f16x2;
typedef __attribute__((ext_vector_type(2))) __fp16   h16x2;

#define H1 50
#define H2 20

union W4 { unsigned u[4]; f16x8 v; };
union W8 { _Float16 h[8]; f16x8 v; };

static __device__ inline unsigned pk_u32(float a, float b) {
    h16x2 p = __builtin_amdgcn_cvt_pkrtz(a, b);
    unsigned u; __builtin_memcpy(&u, &p, 4); return u;
}
static __device__ inline unsigned pkmax0(unsigned a) {
    unsigned r;
    asm("v_pk_max_f16 %0, %1, %2" : "=v"(r) : "v"(a), "v"(0u));
    return r;
}
static __device__ inline float dot2(unsigned a, unsigned b, float c) {
    f16x2 av, bv;
    __builtin_memcpy(&av, &a, 4);
    __builtin_memcpy(&bv, &b, 4);
    return __builtin_amdgcn_fdot2(av, bv, c, false);
}

__global__ __launch_bounds__(256, 5) void neumf_mfma16(
    const int* __restrict__ users, const int* __restrict__ items,
    const float* __restrict__ eU, const float* __restrict__ eV,
    const float* __restrict__ W1, const float* __restrict__ b1,
    const float* __restrict__ W2, const float* __restrict__ b2,
    const float* __restrict__ W3, const float* __restrict__ b3,
    float* __restrict__ out, int n, int nTiles, int tilesPerWave, int nU)
{
    const int lane = threadIdx.x & 63;
    const int wid  = blockIdx.x * (blockDim.x >> 6) + (threadIdx.x >> 6);
    const int g    = lane >> 4;     // group: 0=eU(k0-3), 1=eV(k4-7), 2=bias(k8), 3=pad
    const int r15  = lane & 15;     // sample within tile / weight row within m-tile

    // ---- stage eU in LDS as packed f16 (611*8B), coalesced f32 reads ----
    __shared__ uint2 ldsU[616];
    for (int r = threadIdx.x; r < nU; r += 256) {
        float4 t = reinterpret_cast<const float4*>(eU)[r];
        ldsU[r] = make_uint2(pk_u32(t.x, t.y), pk_u32(t.z, t.w));
    }
    __syncthreads();

    // ---- A1: W1 (50x8) as 4 m-tiles of 16; K=32 (k0-7 = W1, k8 = b1) ----
    f16x8 a1[4];
#pragma unroll
    for (int mt = 0; mt < 4; ++mt) {
        int m = 16 * mt + r15;
        W8 f;
#pragma unroll
        for (int e = 0; e < 8; ++e) {
            int k = 4 * g + (e & 3) + 16 * (e >> 2);
            float w = 0.f;
            if (m < H1) {
                if (k < 8)       w = W1[m * 8 + k];
                else if (k == 8) w = b1[m];
            }
            f.h[e] = (_Float16)w;
        }
        a1[mt] = f.v;
    }

    // ---- A2: W2 (20x50), 2 m-tiles x 2 k-tiles of K=32 (k50 = b2) ----
    f16x8 a2[2][2];
#pragma unroll
    for (int mt = 0; mt < 2; ++mt) {
#pragma unroll
        for (int kt = 0; kt < 2; ++kt) {
            int m = 16 * mt + r15;
            W8 f;
#pragma unroll
            for (int e = 0; e < 8; ++e) {
                int k = 32 * kt + 4 * g + (e & 3) + 16 * (e >> 2);
                float w = 0.f;
                if (m < H2) {
                    if (k < H1)       w = W2[m * H1 + k];
                    else if (k == H1) w = b2[m];
                }
                f.h[e] = (_Float16)w;
            }
            a2[mt][kt] = f.v;
        }
    }

    // ---- W3 coeff words per lane (m = 4g+r for d2a, 16+4g+r for d2b) ----
    const unsigned w3a = pk_u32(W3[4 * g], W3[4 * g + 1]);
    const unsigned w3b = pk_u32(W3[4 * g + 2], W3[4 * g + 3]);
    const unsigned w3c = (g == 0) ? pk_u32(W3[16], W3[17]) : 0u;
    const unsigned w3d = (g == 0) ? pk_u32(W3[18], W3[19]) : 0u;
    const float bias3 = b3[0];

    const int* ip = (g == 1) ? items : users;
    const unsigned gconst = (g == 2) ? 0x00003C00u : 0u;  // B1 u[0] for g>=2

    const int t0 = wid * tilesPerWave;
    const int t1 = min(t0 + tilesPerWave, nTiles);
    if (t0 >= t1) return;
    const int tl = t1 - 1;

    // ---- pipeline: gather 1 ahead (g1 lanes), idx 2 ahead (g<2 lanes) ----
    int idx_cur = 0, idx_next = 0;
    if (g < 2) idx_cur = ip[16 * t0 + r15];
    float4 gv_cur;
    if (g == 1) gv_cur = *reinterpret_cast<const float4*>(eV + 4 * (size_t)idx_cur);
    if (g < 2) idx_next = ip[16 * min(t0 + 1, tl) + r15];

    for (int T = t0; T < t1; ++T) {
        float4 gv_next;
        if (g == 1) gv_next = *reinterpret_cast<const float4*>(eV + 4 * (size_t)idx_next);
        int idx_nn = 0;
        if (g < 2) idx_nn = ip[16 * min(T + 2, tl) + r15];

        // current-tile B1 words per group
        uint2 cw;
        if (g == 0) cw = ldsU[idx_cur];
        else if (g == 1) cw = make_uint2(pk_u32(gv_cur.x, gv_cur.y),
                                         pk_u32(gv_cur.z, gv_cur.w));
        else cw = make_uint2(gconst, 0u);

        W4 bf1;
        bf1.u[0] = cw.x;
        bf1.u[1] = cw.y;
        bf1.u[2] = 0u;      // k>=16 all zero
        bf1.u[3] = 0u;

        // ---- layer 1: 4 independent short MFMAs ----
        f32x4 z4 = {0.f, 0.f, 0.f, 0.f};
        f32x4 d1[4];
#pragma unroll
        for (int mt = 0; mt < 4; ++mt)
            d1[mt] = __builtin_amdgcn_mfma_f32_16x16x32_f16(a1[mt], bf1.v, z4, 0, 0, 0);

        // ---- pack h1 -> two K=32 B-fragments ----
        W4 bk0, bk1;
        bk0.u[0] = pkmax0(pk_u32(d1[0][0], d1[0][1]));
        bk0.u[1] = pkmax0(pk_u32(d1[0][2], d1[0][3]));
        bk0.u[2] = pkmax0(pk_u32(d1[1][0], d1[1][1]));
        bk0.u[3] = pkmax0(pk_u32(d1[1][2], d1[1][3]));
        bk1.u[0] = pkmax0(pk_u32(d1[2][0], d1[2][1]));
        bk1.u[1] = pkmax0(pk_u32(d1[2][2], d1[2][3]));
        bk1.u[2] = pkmax0(pk_u32(d1[3][0], d1[3][1]));
        bk1.u[3] = (g == 0) ? 0x00003C00u                  // k=50 bias = 1.0
                            : pkmax0(pk_u32(d1[3][2], d1[3][3]));

        // ---- layer 2: 2 m-tiles x 2 k-tiles ----
        f32x4 d2a, d2b;
        d2a = __builtin_amdgcn_mfma_f32_16x16x32_f16(a2[0][0], bk0.v, z4, 0, 0, 0);
        d2a = __builtin_amdgcn_mfma_f32_16x16x32_f16(a2[0][1], bk1.v, d2a, 0, 0, 0);
        d2b = __builtin_amdgcn_mfma_f32_16x16x32_f16(a2[1][0], bk0.v, z4, 0, 0, 0);
        d2b = __builtin_amdgcn_mfma_f32_16x16x32_f16(a2[1][1], bk1.v, d2b, 0, 0, 0);

        // ---- layer 3: per-lane dot2 partials + cross-group reduce ----
        unsigned pa = pkmax0(pk_u32(d2a[0], d2a[1]));   // m = 4g, 4g+1
        unsigned pb = pkmax0(pk_u32(d2a[2], d2a[3]));   // m = 4g+2, 4g+3
        unsigned pc = pkmax0(pk_u32(d2b[0], d2b[1]));   // m = 16+4g.. (g0 real)
        unsigned pd = pkmax0(pk_u32(d2b[2], d2b[3]));
        float pt = dot2(pa, w3a, dot2(pb, w3b, dot2(pc, w3c, dot2(pd, w3d, 0.f))));
        pt += __shfl_xor(pt, 16, 64);
        pt += __shfl_xor(pt, 32, 64);

        if (g == 0) out[16 * T + r15] = pt + bias3;

        gv_cur = gv_next; idx_cur = idx_next; idx_next = idx_nn;
    }
}

extern "C" void kernel_launch(void* const* d_in, const int* in_sizes, int n_in,
                              void* d_out, int out_size, void* d_ws, size_t ws_size,
                              hipStream_t stream) {
    const int*   users = (const int*)d_in[0];
    const int*   items = (const int*)d_in[1];
    const float* eU    = (const float*)d_in[2];
    const float* eV    = (const float*)d_in[3];
    const float* W1    = (const float*)d_in[4];
    const float* b1    = (const float*)d_in[5];
    const float* W2    = (const float*)d_in[6];
    const float* b2    = (const float*)d_in[7];
    const float* W3    = (const float*)d_in[8];
    const float* b3    = (const float*)d_in[9];
    float*       out   = (float*)d_out;

    int n  = in_sizes[0];
    int nU = in_sizes[2] / 4;           // 611

    int nTiles = (n + 15) / 16;
    // one resident generation at 5 waves/SIMD: 1280 blocks * 4 waves = 5120
    int blocks = 1280, threads = 256;
    int totalWaves = blocks * (threads / 64);
    int tilesPerWave = (nTiles + totalWaves - 1) / totalWaves;
    neumf_mfma16<<<blocks, threads, 0, stream>>>(users, items, eU, eV,
                                                 W1, b1, W2, b2, W3, b3,
                                                 out, n, nTiles, tilesPerWave, nU);
}

// Round 17
// 25.378 us; speedup vs baseline: 1.5511x; 1.5511x over previous
//
#include <hip/hip_runtime.h>
#include <hip/hip_fp16.h>

// NeuMF forward, dual-tile (64 samples/iter), both tiles in the R13-validated
// orientation via v_mfma_f32_32x32x16_f16.
// Layouts (blocked-K, lane half h = lane>>5):
//   A[m][k]: m = lane&31,  k = 4h + (e&3) + 8*(e>>2), e=0..7
//   B[k][n]: n = lane&31,  k = same formula
//   D[m][n]: n = lane&31,  m = (r&3) + 8*(r>>2) + 4h,  r=0..15
// Chain identity: D regs 8q..8q+7 of m-tile mt ARE B-frag words of k-tile
// kt=2mt+q next layer (same lane/sample).
// Tile A = samples 64T+0..31, tile B = samples 64T+32..63. For BOTH tiles:
// h=0 lanes supply eU (k0-3 via LDS) + bias k=8; h=1 lanes supply eV (k4-7
// via gather). h=0 lanes: 2 LDS reads/iter; h=1 lanes: 2 gathers/iter.
// Two independent MFMA/pack chains per iteration -> 2x per-wave ILP.
// Layer 3 = R13's exact path per tile: a3-MFMA over m=0..15 + dot2 tail
// (m=16..19, h=0). Tile-B result shfl_xor(32)'d to h=1 lanes for one
// coalesced 64-lane store.
// Biases: B1 elem4 (k=8, h=0) = 1.0 -> A1 col8 = b1; layer2 kt3 word u[1] =
// {1.0,0} on h=0 (A2 col50 = b2); b3 seeds the dot2 tail.

typedef __attribute__((ext_vector_type(16))) float    f32x16;
typedef __attribute__((ext_vector_type(8)))  _Float16 f16x8;
typedef __attribute__((ext_vector_type(2)))  _Float16 f16x2;
typedef __attribute__((ext_vector_type(2)))  __fp16   h16x2;

#define H1 50
#define H2 20

union W4 { unsigned u[4]; f16x8 v; };
union W8 { _Float16 h[8]; f16x8 v; };

static __device__ inline unsigned pk_u32(float a, float b) {
    h16x2 p = __builtin_amdgcn_cvt_pkrtz(a, b);
    unsigned u; __builtin_memcpy(&u, &p, 4); return u;
}
static __device__ inline unsigned pkmax0(unsigned a) {
    unsigned r;
    asm("v_pk_max_f16 %0, %1, %2" : "=v"(r) : "v"(a), "v"(0u));
    return r;
}
static __device__ inline float dot2(unsigned a, unsigned b, float c) {
    f16x2 av, bv;
    __builtin_memcpy(&av, &a, 4);
    __builtin_memcpy(&bv, &b, 4);
    return __builtin_amdgcn_fdot2(av, bv, c, false);
}

__global__ __launch_bounds__(256, 3) void neumf_dual(
    const int* __restrict__ users, const int* __restrict__ items,
    const float* __restrict__ eU, const float* __restrict__ eV,
    const float* __restrict__ W1, const float* __restrict__ b1,
    const float* __restrict__ W2, const float* __restrict__ b2,
    const float* __restrict__ W3, const float* __restrict__ b3,
    float* __restrict__ out, int n, int nIter, int itersPerWave, int nU)
{
    const int lane = threadIdx.x & 63;
    const int wid  = blockIdx.x * (blockDim.x >> 6) + (threadIdx.x >> 6);
    const int h    = lane >> 5;
    const int r31  = lane & 31;

    // ---- stage eU in LDS as packed f16 ----
    __shared__ uint2 ldsU[616];
    for (int r = threadIdx.x; r < nU; r += 256) {
        float4 t = reinterpret_cast<const float4*>(eU)[r];
        ldsU[r] = make_uint2(pk_u32(t.x, t.y), pk_u32(t.z, t.w));
    }
    __syncthreads();

    // ---- A1: W1 (50x8) as 2 m-tiles of 32, K=16 (cols 0-7 = W1, col 8 = b1) ----
    f16x8 a1[2];
#pragma unroll
    for (int mt = 0; mt < 2; ++mt) {
        int m = 32 * mt + r31;
        float w[8] = {0.f,0.f,0.f,0.f,0.f,0.f,0.f,0.f};
        if (m < H1) {
#pragma unroll
            for (int i = 0; i < 4; ++i) w[i] = W1[m * 8 + 4 * h + i];   // k = 4h+i
            if (h == 0) w[4] = b1[m];                                   // k = 8
        }
        W8 f;
#pragma unroll
        for (int i = 0; i < 8; ++i) f.h[i] = (_Float16)w[i];
        a1[mt] = f.v;
    }

    // ---- A2: W2 (20x50) 1 m-tile, K=64 as 4 k-tiles (col 50 = b2) ----
    f16x8 a2[4];
    {
        int m = r31;
#pragma unroll
        for (int kt = 0; kt < 4; ++kt) {
            float w[8] = {0.f,0.f,0.f,0.f,0.f,0.f,0.f,0.f};
            if (m < H2) {
#pragma unroll
                for (int e = 0; e < 8; ++e) {
                    int k = 16 * kt + 4 * h + (e & 3) + 8 * (e >> 2);
                    if (k < H1)       w[e] = W2[m * H1 + k];
                    else if (k == H1) w[e] = b2[m];
                }
            }
            W8 f;
#pragma unroll
            for (int e = 0; e < 8; ++e) f.h[e] = (_Float16)w[e];
            a2[kt] = f.v;
        }
    }

    // ---- A3: W3 k=0..15 broadcast over all rows ----
    f16x8 a3;
    {
        W8 f;
#pragma unroll
        for (int e = 0; e < 8; ++e) {
            int k = 4 * h + (e & 3) + 8 * (e >> 2);
            f.h[e] = (_Float16)W3[k];
        }
        a3 = f.v;
    }
    // tail pairs k={16,17},{18,19} as packed f16 (h=0 lanes; h=1 contribute 0)
    const unsigned w3p0 = h ? 0u : pk_u32(W3[16], W3[17]);
    const unsigned w3p1 = h ? 0u : pk_u32(W3[18], W3[19]);
    const float bias3 = b3[0];

    const int*     ip  = h ? items : users;
    const unsigned w2c = h ? 0u : 0x00003C00u;  // {1.0h,0}: B1 k=8 bias AND kt3 k=50 bias

    const int t0 = wid * itersPerWave;
    const int t1 = min(t0 + itersPerWave, nIter);
    if (t0 >= t1) return;
    const int tl = t1 - 1;

    // ---- prologue: both tiles' idx + gathers one iteration ahead ----
    int iA_cur = ip[64 * t0 + r31];
    int iB_cur = ip[64 * t0 + 32 + r31];
    float4 gvA_cur, gvB_cur;
    if (h) {
        gvA_cur = *reinterpret_cast<const float4*>(eV + 4 * (size_t)iA_cur);
        gvB_cur = *reinterpret_cast<const float4*>(eV + 4 * (size_t)iB_cur);
    }
    int iA_next = ip[64 * min(t0 + 1, tl) + r31];
    int iB_next = ip[64 * min(t0 + 1, tl) + 32 + r31];

    for (int T = t0; T < t1; ++T) {
        // issue next gathers + next-next idx first
        float4 gvA_next, gvB_next;
        if (h) {
            gvA_next = *reinterpret_cast<const float4*>(eV + 4 * (size_t)iA_next);
            gvB_next = *reinterpret_cast<const float4*>(eV + 4 * (size_t)iB_next);
        }
        int iA_nn = ip[64 * min(T + 2, tl) + r31];
        int iB_nn = ip[64 * min(T + 2, tl) + 32 + r31];

        // current-tile input words (R13 orientation for BOTH tiles)
        uint2 cwA, cwB;
        if (h) {
            cwA = make_uint2(pk_u32(gvA_cur.x, gvA_cur.y), pk_u32(gvA_cur.z, gvA_cur.w));
            cwB = make_uint2(pk_u32(gvB_cur.x, gvB_cur.y), pk_u32(gvB_cur.z, gvB_cur.w));
        } else {
            cwA = ldsU[iA_cur];
            cwB = ldsU[iB_cur];
        }

        W4 bfA, bfB;
        bfA.u[0] = cwA.x; bfA.u[1] = cwA.y; bfA.u[2] = w2c; bfA.u[3] = 0u;
        bfB.u[0] = cwB.x; bfB.u[1] = cwB.y; bfB.u[2] = w2c; bfB.u[3] = 0u;

        // ---- layer 1: 4 independent MFMAs (2 per tile) ----
        f32x16 z = {0.f,0.f,0.f,0.f,0.f,0.f,0.f,0.f,0.f,0.f,0.f,0.f,0.f,0.f,0.f,0.f};
        f32x16 d1A0 = __builtin_amdgcn_mfma_f32_32x32x16_f16(a1[0], bfA.v, z, 0, 0, 0);
        f32x16 d1B0 = __builtin_amdgcn_mfma_f32_32x32x16_f16(a1[0], bfB.v, z, 0, 0, 0);
        f32x16 d1A1 = __builtin_amdgcn_mfma_f32_32x32x16_f16(a1[1], bfA.v, z, 0, 0, 0);
        f32x16 d1B1 = __builtin_amdgcn_mfma_f32_32x32x16_f16(a1[1], bfB.v, z, 0, 0, 0);

        // ---- layer 2: two interleaved independent chains (R13 kt scheme) ----
        f32x16 d2A = z, d2B = z;
#pragma unroll
        for (int kt = 0; kt < 3; ++kt) {
            const int q = kt & 1;
            const f32x16& sA = (kt < 2) ? d1A0 : d1A1;
            const f32x16& sB = (kt < 2) ? d1B0 : d1B1;
            W4 bA, bB;
#pragma unroll
            for (int j = 0; j < 4; ++j) {
                bA.u[j] = pkmax0(pk_u32(sA[8*q + 2*j], sA[8*q + 2*j + 1]));
                bB.u[j] = pkmax0(pk_u32(sB[8*q + 2*j], sB[8*q + 2*j + 1]));
            }
            d2A = __builtin_amdgcn_mfma_f32_32x32x16_f16(a2[kt], bA.v, d2A, 0, 0, 0);
            d2B = __builtin_amdgcn_mfma_f32_32x32x16_f16(a2[kt], bB.v, d2B, 0, 0, 0);
        }
        {   // kt=3: units 48,49 + b2-bias const word (k=50 on h=0)
            W4 bA, bB;
            bA.u[0] = pkmax0(pk_u32(d1A1[8], d1A1[9]));
            bB.u[0] = pkmax0(pk_u32(d1B1[8], d1B1[9]));
            bA.u[1] = w2c; bA.u[2] = w2c; bA.u[3] = w2c;
            bB.u[1] = w2c; bB.u[2] = w2c; bB.u[3] = w2c;
            d2A = __builtin_amdgcn_mfma_f32_32x32x16_f16(a2[3], bA.v, d2A, 0, 0, 0);
            d2B = __builtin_amdgcn_mfma_f32_32x32x16_f16(a2[3], bB.v, d2B, 0, 0, 0);
        }

        // ---- layer 3 (R13 path, per tile): a3-MFMA m=0..15 + dot2 tail ----
        W4 b3fA, b3fB;
        b3fA.u[0] = pkmax0(pk_u32(d2A[0], d2A[1]));
        b3fA.u[1] = pkmax0(pk_u32(d2A[2], d2A[3]));
        b3fA.u[2] = pkmax0(pk_u32(d2A[4], d2A[5]));
        b3fA.u[3] = pkmax0(pk_u32(d2A[6], d2A[7]));
        b3fB.u[0] = pkmax0(pk_u32(d2B[0], d2B[1]));
        b3fB.u[1] = pkmax0(pk_u32(d2B[2], d2B[3]));
        b3fB.u[2] = pkmax0(pk_u32(d2B[4], d2B[5]));
        b3fB.u[3] = pkmax0(pk_u32(d2B[6], d2B[7]));
        f32x16 d3A = __builtin_amdgcn_mfma_f32_32x32x16_f16(a3, b3fA.v, z, 0, 0, 0);
        f32x16 d3B = __builtin_amdgcn_mfma_f32_32x32x16_f16(a3, b3fB.v, z, 0, 0, 0);

        unsigned tA0 = pkmax0(pk_u32(d2A[8],  d2A[9]));    // m=16,17 (h=0)
        unsigned tA1 = pkmax0(pk_u32(d2A[10], d2A[11]));   // m=18,19 (h=0)
        unsigned tB0 = pkmax0(pk_u32(d2B[8],  d2B[9]));
        unsigned tB1 = pkmax0(pk_u32(d2B[10], d2B[11]));
        float ptA = dot2(tA0, w3p0, dot2(tA1, w3p1, bias3));  // h=1: = bias3
        float ptB = dot2(tB0, w3p0, dot2(tB1, w3p1, bias3));

        float outA = d3A[0] + ptA;      // valid on h=0 lanes (full tail there)
        float outB = d3B[0] + ptB;      // valid on h=0 lanes
        float outBs = __shfl_xor(outB, 32, 64);   // move tile-B result to h=1

        // coalesced 64-lane store: lanes 0-31 tile A, lanes 32-63 tile B
        out[64 * T + lane] = h ? outBs : outA;

        // rotate pipelines
        gvA_cur = gvA_next; gvB_cur = gvB_next;
        iA_cur = iA_next;   iB_cur = iB_next;
        iA_next = iA_nn;    iB_next = iB_nn;
    }
}

extern "C" void kernel_launch(void* const* d_in, const int* in_sizes, int n_in,
                              void* d_out, int out_size, void* d_ws, size_t ws_size,
                              hipStream_t stream) {
    const int*   users = (const int*)d_in[0];
    const int*   items = (const int*)d_in[1];
    const float* eU    = (const float*)d_in[2];
    const float* eV    = (const float*)d_in[3];
    const float* W1    = (const float*)d_in[4];
    const float* b1    = (const float*)d_in[5];
    const float* W2    = (const float*)d_in[6];
    const float* b2    = (const float*)d_in[7];
    const float* W3    = (const float*)d_in[8];
    const float* b3    = (const float*)d_in[9];
    float*       out   = (float*)d_out;

    int n  = in_sizes[0];
    int nU = in_sizes[2] / 4;           // 611

    int nIter = (n + 63) / 64;          // 64 samples per iteration
    // one generation at 3 waves/SIMD: 768 blocks * 4 waves = 3072 waves
    int blocks = 768, threads = 256;
    int totalWaves = blocks * (threads / 64);
    int itersPerWave = (nIter + totalWaves - 1) / totalWaves;
    neumf_dual<<<blocks, threads, 0, stream>>>(users, items, eU, eV,
                                               W1, b1, W2, b2, W3, b3,
                                               out, n, nIter, itersPerWave, nU);
}

// Round 18
// 23.514 us; speedup vs baseline: 1.6741x; 1.0793x over previous
//
#include <hip/hip_runtime.h>
#include <hip/hip_fp16.h>

// NeuMF forward via full-rate v_mfma_f32_32x32x16_f16 (gfx950). R13 kernel,
// occupancy experiment: __launch_bounds__(256,5) (<=102 VGPR) + 1280 blocks
// -> 5 waves/SIMD (was 4). Loop body unchanged from the validated 23.6us run.
// Layouts (blocked-K, lane half h = lane>>5):
//   A[m][k]: m = lane&31,  k = 4h + (e&3) + 8*(e>>2), e=0..7
//   B[k][n]: n = lane&31,  k = same formula
//   D[m][n]: n = lane&31,  m = (r&3) + 8*(r>>2) + 4h,  r=0..15
// Chain identity: D regs 8q..8q+7 of m-tile mt ARE the B-fragment words of
// k-tile kt=2mt+q for the next layer (same lane, same sample).
// Biases: B1 elem4 (k=8, h=0) = 1.0 -> A1 col 8 = b1; layer-2 bias rides the
// constant word u[1]={1.0,0} (h=0) of kt=3 (k=50 col of A2 = b2); b3 seeds
// the v_dot2 tail. Out-of-range B words (e.g. kt3 k=52,53 on h=1) multiply
// ZERO A-columns -> harmless.

typedef __attribute__((ext_vector_type(16))) float    f32x16;
typedef __attribute__((ext_vector_type(8)))  _Float16 f16x8;
typedef __attribute__((ext_vector_type(2)))  _Float16 f16x2;
typedef __attribute__((ext_vector_type(2)))  __fp16   h16x2;

#define H1 50
#define H2 20

union W4 { unsigned u[4]; f16x8 v; };
union W8 { _Float16 h[8]; f16x8 v; };

static __device__ inline unsigned pk_u32(float a, float b) {
    h16x2 p = __builtin_amdgcn_cvt_pkrtz(a, b);
    unsigned u; __builtin_memcpy(&u, &p, 4); return u;
}
// packed f16 relu (== relu-then-cvt bitwise)
static __device__ inline unsigned pkmax0(unsigned a) {
    unsigned r;
    asm("v_pk_max_f16 %0, %1, %2" : "=v"(r) : "v"(a), "v"(0u));
    return r;
}
// f16x2 dot with f32 accumulate
static __device__ inline float dot2(unsigned a, unsigned b, float c) {
    f16x2 av, bv;
    __builtin_memcpy(&av, &a, 4);
    __builtin_memcpy(&bv, &b, 4);
    return __builtin_amdgcn_fdot2(av, bv, c, false);
}

__global__ __launch_bounds__(256, 5) void neumf_mfma32(
    const int* __restrict__ users, const int* __restrict__ items,
    const float* __restrict__ eU, const float* __restrict__ eV,
    const float* __restrict__ W1, const float* __restrict__ b1,
    const float* __restrict__ W2, const float* __restrict__ b2,
    const float* __restrict__ W3, const float* __restrict__ b3,
    float* __restrict__ out, int n, int nTiles, int tilesPerWave, int nU)
{
    const int lane = threadIdx.x & 63;
    const int wid  = blockIdx.x * (blockDim.x >> 6) + (threadIdx.x >> 6);
    const int h    = lane >> 5;     // 0 = eU side (k 0..3 + bias), 1 = eV side (k 4..7)
    const int r31  = lane & 31;

    // ---- stage eU in LDS as packed f16 (611*8B = 4.9KB), coalesced f32 reads ----
    __shared__ uint2 ldsU[616];
    for (int r = threadIdx.x; r < nU; r += 256) {
        float4 t = reinterpret_cast<const float4*>(eU)[r];
        ldsU[r] = make_uint2(pk_u32(t.x, t.y), pk_u32(t.z, t.w));
    }
    __syncthreads();

    // ---- A1: W1 (50x8) as 2 m-tiles of 32, K=16 (cols 0-7 = W1, col 8 = b1) ----
    f16x8 a1[2];
#pragma unroll
    for (int mt = 0; mt < 2; ++mt) {
        int m = 32 * mt + r31;
        float w[8] = {0.f,0.f,0.f,0.f,0.f,0.f,0.f,0.f};
        if (m < H1) {
#pragma unroll
            for (int i = 0; i < 4; ++i) w[i] = W1[m * 8 + 4 * h + i];   // k = 4h+i
            if (h == 0) w[4] = b1[m];                                   // k = 8
        }
        W8 f;
#pragma unroll
        for (int i = 0; i < 8; ++i) f.h[i] = (_Float16)w[i];
        a1[mt] = f.v;
    }

    // ---- A2: W2 (20x50) 1 m-tile, K=64 as 4 k-tiles (col 50 = b2) ----
    f16x8 a2[4];
    {
        int m = r31;
#pragma unroll
        for (int kt = 0; kt < 4; ++kt) {
            float w[8] = {0.f,0.f,0.f,0.f,0.f,0.f,0.f,0.f};
            if (m < H2) {
#pragma unroll
                for (int e = 0; e < 8; ++e) {
                    int k = 16 * kt + 4 * h + (e & 3) + 8 * (e >> 2);
                    if (k < H1)       w[e] = W2[m * H1 + k];
                    else if (k == H1) w[e] = b2[m];
                }
            }
            W8 f;
#pragma unroll
            for (int e = 0; e < 8; ++e) f.h[e] = (_Float16)w[e];
            a2[kt] = f.v;
        }
    }

    // ---- A3: W3 k=0..15 broadcast over all rows ----
    f16x8 a3;
    {
        W8 f;
#pragma unroll
        for (int e = 0; e < 8; ++e) {
            int k = 4 * h + (e & 3) + 8 * (e >> 2);
            f.h[e] = (_Float16)W3[k];
        }
        a3 = f.v;
    }
    // tail pairs k={16,17},{18,19} as packed f16 (h=0 lanes; h=1 contribute 0)
    const unsigned w3p0 = h ? 0u : pk_u32(W3[16], W3[17]);
    const unsigned w3p1 = h ? 0u : pk_u32(W3[18], W3[19]);
    const float bias3 = b3[0];

    const int*     ip  = h ? items : users;
    const unsigned w2c = h ? 0u : 0x00003C00u;  // {1.0h, 0}: B1 k=8 bias AND kt3 k=50 bias

    const int t0 = wid * tilesPerWave;
    const int t1 = min(t0 + tilesPerWave, nTiles);
    if (t0 >= t1) return;
    const int tl = t1 - 1;

    // ---- pipeline: gather 1 ahead, idx 2 ahead ----
    int idx_cur = ip[32 * t0 + r31];
    float4 gv_cur;
    if (h) gv_cur = *reinterpret_cast<const float4*>(eV + 4 * (size_t)idx_cur);
    int idx_next = ip[32 * min(t0 + 1, tl) + r31];

#pragma unroll 2
    for (int T = t0; T < t1; ++T) {
        float4 gv_next;
        if (h) gv_next = *reinterpret_cast<const float4*>(eV + 4 * (size_t)idx_next);
        int idx_nn = ip[32 * min(T + 2, tl) + r31];

        // current-tile input words: h=1 converts gathered f32, h=0 reads LDS f16
        uint2 cw;
        if (h) cw = make_uint2(pk_u32(gv_cur.x, gv_cur.y), pk_u32(gv_cur.z, gv_cur.w));
        else   cw = ldsU[idx_cur];                       // ds_read_b64

        // ---- B1: f16 pairs land directly in elems 0..3 (k = 4h..4h+3) ----
        W4 bf1;
        bf1.u[0] = cw.x;
        bf1.u[1] = cw.y;
        bf1.u[2] = w2c;         // k=8 bias (h=0)
        bf1.u[3] = 0u;

        // ---- layer 1: 2 MFMAs ----
        f32x16 z = {0.f,0.f,0.f,0.f,0.f,0.f,0.f,0.f,0.f,0.f,0.f,0.f,0.f,0.f,0.f,0.f};
        f32x16 d1[2];
        d1[0] = __builtin_amdgcn_mfma_f32_32x32x16_f16(a1[0], bf1.v, z, 0, 0, 0);
        d1[1] = __builtin_amdgcn_mfma_f32_32x32x16_f16(a1[1], bf1.v, z, 0, 0, 0);

        // ---- layer 2: 4 MFMAs; kt=0..2 full packs, kt=3 trimmed ----
        f32x16 d2 = z;
#pragma unroll
        for (int kt = 0; kt < 3; ++kt) {
            const int mt = kt >> 1, q = kt & 1;
            W4 bf;
#pragma unroll
            for (int j = 0; j < 4; ++j)
                bf.u[j] = pkmax0(pk_u32(d1[mt][8 * q + 2 * j], d1[mt][8 * q + 2 * j + 1]));
            d2 = __builtin_amdgcn_mfma_f32_32x32x16_f16(a2[kt], bf.v, d2, 0, 0, 0);
        }
        {   // kt=3: real k = 48,49 (units) + 50 (b2 bias const); rest zero-A
            W4 bf;
            bf.u[0] = pkmax0(pk_u32(d1[1][8], d1[1][9]));
            bf.u[1] = w2c;      // {1.0,0} on h=0 -> k=50 bias column
            bf.u[2] = w2c;      // garbage-safe (A cols zero)
            bf.u[3] = w2c;
            d2 = __builtin_amdgcn_mfma_f32_32x32x16_f16(a2[3], bf.v, d2, 0, 0, 0);
        }

        // ---- layer 3: MFMA over k=0..15 (d2 regs 0..7) + dot2 tail k=16..19 ----
        W4 b3f;
        b3f.u[0] = pkmax0(pk_u32(d2[0], d2[1]));
        b3f.u[1] = pkmax0(pk_u32(d2[2], d2[3]));
        b3f.u[2] = pkmax0(pk_u32(d2[4], d2[5]));
        b3f.u[3] = pkmax0(pk_u32(d2[6], d2[7]));
        f32x16 d3 = __builtin_amdgcn_mfma_f32_32x32x16_f16(a3, b3f.v, z, 0, 0, 0);

        unsigned t0w = pkmax0(pk_u32(d2[8],  d2[9]));    // m=16,17 (h=0)
        unsigned t1w = pkmax0(pk_u32(d2[10], d2[11]));   // m=18,19 (h=0)
        float pt = dot2(t0w, w3p0, dot2(t1w, w3p1, bias3));

        if (!h) out[32 * T + r31] = d3[0] + pt;          // d3 rows all equal

        gv_cur = gv_next; idx_cur = idx_next; idx_next = idx_nn;
    }
}

extern "C" void kernel_launch(void* const* d_in, const int* in_sizes, int n_in,
                              void* d_out, int out_size, void* d_ws, size_t ws_size,
                              hipStream_t stream) {
    const int*   users = (const int*)d_in[0];
    const int*   items = (const int*)d_in[1];
    const float* eU    = (const float*)d_in[2];
    const float* eV    = (const float*)d_in[3];
    const float* W1    = (const float*)d_in[4];
    const float* b1    = (const float*)d_in[5];
    const float* W2    = (const float*)d_in[6];
    const float* b2    = (const float*)d_in[7];
    const float* W3    = (const float*)d_in[8];
    const float* b3    = (const float*)d_in[9];
    float*       out   = (float*)d_out;

    int n  = in_sizes[0];
    int nU = in_sizes[2] / 4;           // 611

    int nTiles = (n + 31) / 32;
    // one resident generation at 5 waves/SIMD: 1280 blocks * 4 waves = 5120
    //                                        = 256 CU * 4 SIMD * 5 waves/SIMD
    int blocks = 1280, threads = 256;
    int totalWaves = blocks * (threads / 64);
    int tilesPerWave = (nTiles + totalWaves - 1) / totalWaves;
    neumf_mfma32<<<blocks, threads, 0, stream>>>(users, items, eU, eV,
                                                 W1, b1, W2, b2, W3, b3,
                                                 out, n, nTiles, tilesPerWave, nU);
}